// Round 12
// baseline (378.229 us; speedup 1.0000x reference)
//
#include <hip/hip_runtime.h>
#include <hip/hip_bf16.h>
#include <stdint.h>

#define K_DIM 4096
#define N_DIM 4096
#define TOKENS 8192

#define BM 256
#define BN 256
#define BK 64
#define NT (K_DIM / BK)        // 64 k-tiles

// LDS: 2 bufs x { A[256r][128B row] | B[256c][128B row] } = 2 x 64 KB.
// 16 KB units: A0(rows0-127) A1(rows128-255) B0 B1.  Row = 8 chunks of 16B,
// phys chunk = logical chunk ^ (row&7)  (conflict-free frag reads, verified r3-r10).
#define BUF_BYTES 65536
#define BOFS 32768
#define KH_BYTES 16384

typedef __attribute__((ext_vector_type(8))) short bf16x8;
typedef __attribute__((ext_vector_type(4))) float f32x4;

#define LDSV(p) ((__attribute__((address_space(3))) void*)(p))
#define GLBV(p) ((const __attribute__((address_space(1))) void*)(p))
#define MEMFENCE asm volatile("" ::: "memory")

__device__ inline unsigned short f2bf(float f) {
    union { float f; unsigned u; } v; v.f = f;
    unsigned r = v.u + 0x7FFF + ((v.u >> 16) & 1);   // RNE
    return (unsigned short)(r >> 16);
}

// ------- fused prepass: blocks [0,16384) convert x fp32->bf16;
//         blocks [16384,17408) GPTQ-dequant -> W^T bf16 [N][K] -------
#define CVT_BLOCKS 16384
__global__ __launch_bounds__(256) void prep_kernel(
    const float* __restrict__ x, unsigned short* __restrict__ xbf,
    const int* __restrict__ qweight, const int* __restrict__ qzeros,
    const float* __restrict__ scales, unsigned short* __restrict__ wt)
{
    const int b = blockIdx.x;
    if (b < CVT_BLOCKS) {
        size_t idx = ((size_t)b * 256 + threadIdx.x) * 8;
        const float4 v0 = *reinterpret_cast<const float4*>(&x[idx]);
        const float4 v1 = *reinterpret_cast<const float4*>(&x[idx + 4]);
        ushort4 h0, h1;
        h0.x = f2bf(v0.x); h0.y = f2bf(v0.y); h0.z = f2bf(v0.z); h0.w = f2bf(v0.w);
        h1.x = f2bf(v1.x); h1.y = f2bf(v1.y); h1.z = f2bf(v1.z); h1.w = f2bf(v1.w);
        *reinterpret_cast<ushort4*>(&xbf[idx]) = h0;
        *reinterpret_cast<ushort4*>(&xbf[idx + 4]) = h1;
    } else {
        const int idx = (b - CVT_BLOCKS) * 256 + threadIdx.x;
        const int kb = idx >> 12;            // 0..63  (block of 64 k)
        const int n  = idx & (N_DIM - 1);
        const int kr0 = kb * 8;
        const int g = kb >> 1;               // group: (kb*64)/128
        const float sc = scales[(size_t)g * N_DIM + n];
        const int zq = qzeros[(size_t)g * (N_DIM / 8) + (n >> 3)];
        const float zf = (float)(((zq >> ((n & 7) * 4)) & 0xF) + 1);

        unsigned short* dst = &wt[(size_t)n * K_DIM + kb * 64];
#pragma unroll
        for (int i = 0; i < 8; i++) {
            const int q = qweight[(size_t)(kr0 + i) * N_DIM + n];
            bf16x8 wv;
#pragma unroll
            for (int s = 0; s < 8; s++) {
                const float w = (float)((q >> (s * 4)) & 0xF) - zf;
                wv[s] = (short)f2bf(sc * w);
            }
            *reinterpret_cast<bf16x8*>(&dst[i * 8]) = wv;
        }
    }
}

// ----- main GEMM: 256x256, 8 waves, 1-barrier/tile software-pipelined, dbuf-2 -----
// r10 verified schedule; staging addresses held in 8 persistent per-thread
// pointers advanced +BK per tile (kills per-tile 64-bit addr recompute), and
// unroll-2 makes cb/cbn compile-time so LDS offsets fold to immediates.
__global__ __launch_bounds__(512, 2) void gemm_sp_kernel(
    const unsigned short* __restrict__ xbf, const unsigned short* __restrict__ wt,
    const float* __restrict__ bias, float* __restrict__ out)
{
    __shared__ __align__(16) char lds[2 * BUF_BYTES];   // 128 KB

    const int tid  = threadIdx.x;
    const int lane = tid & 63;
    const int wave = tid >> 6;
    const int wm = wave >> 2;        // 0..1 : 128-row M slice
    const int wn = wave & 3;         // 0..3 : 64-col N slice
    const int fr = lane & 15;
    const int fq = lane >> 4;

    const int m0 = blockIdx.x * BM;
    const int n0 = blockIdx.y * BN;

    // staging geometry: gload covers 8 rows x 8 chunks; source chunk pre-permuted
    const int srow = wave * 8 + (lane >> 3);
    const int k8   = (lane & 7) ^ ((lane >> 3) & 7);

    // persistent staging pointers (advanced +BK per tile)
    const unsigned short* pa0 = xbf + (size_t)(m0 + srow) * K_DIM + k8 * 8;
    const unsigned short* pa1 = pa0 + (size_t)64  * K_DIM;
    const unsigned short* pa2 = pa0 + (size_t)128 * K_DIM;
    const unsigned short* pa3 = pa0 + (size_t)192 * K_DIM;
    const unsigned short* pb0 = wt  + (size_t)(n0 + srow) * K_DIM + k8 * 8;
    const unsigned short* pb1 = pb0 + (size_t)64  * K_DIM;
    const unsigned short* pb2 = pb0 + (size_t)128 * K_DIM;
    const unsigned short* pb3 = pb0 + (size_t)192 * K_DIM;

    // fragment read offsets
    const int cx0 = (fq ^ (fr & 7)) << 4;          // ks=0 chunk byte
    const int cx1 = ((4 + fq) ^ (fr & 7)) << 4;    // ks=1 chunk byte
    const int aoffs = wm * KH_BYTES + fr * 128;                              // + mi*2048
    const int boffs = BOFS + (wn >> 1) * KH_BYTES + ((wn & 1) * 64 + fr) * 128;  // + ni*2048

    f32x4 acc[8][4];
#pragma unroll
    for (int i = 0; i < 8; i++)
#pragma unroll
        for (int j = 0; j < 4; j++) acc[i][j] = (f32x4){0.f, 0.f, 0.f, 0.f};

    // stage one whole tile into buffer at byte base `dst` from current pointers
#define STAGE_TILE_P(dst) do {                                                  \
    __builtin_amdgcn_global_load_lds(GLBV(pa0), LDSV(lds + (dst) + wave * 1024), 16, 0, 0);                        \
    __builtin_amdgcn_global_load_lds(GLBV(pa1), LDSV(lds + (dst) + 8192 + wave * 1024), 16, 0, 0);                 \
    __builtin_amdgcn_global_load_lds(GLBV(pa2), LDSV(lds + (dst) + KH_BYTES + wave * 1024), 16, 0, 0);             \
    __builtin_amdgcn_global_load_lds(GLBV(pa3), LDSV(lds + (dst) + KH_BYTES + 8192 + wave * 1024), 16, 0, 0);      \
    __builtin_amdgcn_global_load_lds(GLBV(pb0), LDSV(lds + (dst) + BOFS + wave * 1024), 16, 0, 0);                 \
    __builtin_amdgcn_global_load_lds(GLBV(pb1), LDSV(lds + (dst) + BOFS + 8192 + wave * 1024), 16, 0, 0);          \
    __builtin_amdgcn_global_load_lds(GLBV(pb2), LDSV(lds + (dst) + BOFS + KH_BYTES + wave * 1024), 16, 0, 0);      \
    __builtin_amdgcn_global_load_lds(GLBV(pb3), LDSV(lds + (dst) + BOFS + KH_BYTES + 8192 + wave * 1024), 16, 0, 0); } while (0)

#define ADVANCE_PTRS do { pa0 += BK; pa1 += BK; pa2 += BK; pa3 += BK;           \
                          pb0 += BK; pb1 += BK; pb2 += BK; pb3 += BK; } while (0)

#define LD8(off) (*reinterpret_cast<const bf16x8*>(lds + (off)))

    // ---- prologue: stage tile 0, advance to tile 1, wait, barrier, preload
    STAGE_TILE_P(0);
    ADVANCE_PTRS;
    asm volatile("s_waitcnt vmcnt(0)" ::: "memory");
    __builtin_amdgcn_s_barrier();

    bf16x8 afA[4][2], afB[4][2], b0[2][2], b1[2][2];
#pragma unroll
    for (int mi = 0; mi < 4; ++mi) {
        afA[mi][0] = LD8(aoffs + mi * 2048 + cx0);
        afA[mi][1] = LD8(aoffs + mi * 2048 + cx1);
    }
#pragma unroll
    for (int ni = 0; ni < 2; ++ni) {
        b0[ni][0] = LD8(boffs + ni * 2048 + cx0);
        b0[ni][1] = LD8(boffs + ni * 2048 + cx1);
        b1[ni][0] = LD8(boffs + (ni + 2) * 2048 + cx0);
        b1[ni][1] = LD8(boffs + (ni + 2) * 2048 + cx1);
    }

#pragma unroll 2
    for (int t = 0; t < NT; ++t) {
        const int cb  = (t & 1) * BUF_BYTES;
        const int cbn = cb ^ BUF_BYTES;
        const bool more = (t + 1) < NT;

        // S1: stage whole tile t+1 into the opposite buffer, advance pointers
        if (more) { STAGE_TILE_P(cbn); ADVANCE_PTRS; }

        // S2: afB <- af1(t)
#pragma unroll
        for (int mi = 0; mi < 4; ++mi) {
            afB[mi][0] = LD8(cb + aoffs + (mi + 4) * 2048 + cx0);
            afB[mi][1] = LD8(cb + aoffs + (mi + 4) * 2048 + cx1);
        }
        __builtin_amdgcn_sched_barrier(0);

        // C1: afA x b1 -> Q01 FIRST (b1 long-drained), then afA x b0 -> Q00
        __builtin_amdgcn_s_setprio(1);
#pragma unroll
        for (int mi = 0; mi < 4; ++mi)
#pragma unroll
            for (int ni = 0; ni < 2; ++ni)
#pragma unroll
                for (int ks = 0; ks < 2; ++ks)
                    acc[mi][ni + 2] = __builtin_amdgcn_mfma_f32_16x16x32_bf16(
                        afA[mi][ks], b1[ni][ks], acc[mi][ni + 2], 0, 0, 0);
#pragma unroll
        for (int mi = 0; mi < 4; ++mi)
#pragma unroll
            for (int ni = 0; ni < 2; ++ni)
#pragma unroll
                for (int ks = 0; ks < 2; ++ks)
                    acc[mi][ni] = __builtin_amdgcn_mfma_f32_16x16x32_bf16(
                        afA[mi][ks], b0[ni][ks], acc[mi][ni], 0, 0, 0);
        __builtin_amdgcn_s_setprio(0);
        __builtin_amdgcn_sched_barrier(0);

        // C2: afB x b1 -> Q11   (16 MFMA; b1 dies here)
        __builtin_amdgcn_s_setprio(1);
#pragma unroll
        for (int mi = 0; mi < 4; ++mi)
#pragma unroll
            for (int ni = 0; ni < 2; ++ni)
#pragma unroll
                for (int ks = 0; ks < 2; ++ks)
                    acc[mi + 4][ni + 2] = __builtin_amdgcn_mfma_f32_16x16x32_bf16(
                        afB[mi][ks], b1[ni][ks], acc[mi + 4][ni + 2], 0, 0, 0);
        __builtin_amdgcn_s_setprio(0);

        // boundary: own stages (issued a 48-MFMA window ago) land; sync all waves
        asm volatile("s_waitcnt vmcnt(0)" ::: "memory");
        MEMFENCE; __builtin_amdgcn_s_barrier(); MEMFENCE;

        // S7a: afA <- af0(t+1), b1 <- B1(t+1)   (12 reads, overlap C3)
        if (more) {
#pragma unroll
            for (int mi = 0; mi < 4; ++mi) {
                afA[mi][0] = LD8(cbn + aoffs + mi * 2048 + cx0);
                afA[mi][1] = LD8(cbn + aoffs + mi * 2048 + cx1);
            }
#pragma unroll
            for (int ni = 0; ni < 2; ++ni) {
                b1[ni][0] = LD8(cbn + boffs + (ni + 2) * 2048 + cx0);
                b1[ni][1] = LD8(cbn + boffs + (ni + 2) * 2048 + cx1);
            }
        }
        __builtin_amdgcn_sched_barrier(0);

        // C3: afB x b0 -> Q10   (16 MFMA; b0 dies here)
        __builtin_amdgcn_s_setprio(1);
#pragma unroll
        for (int mi = 0; mi < 4; ++mi)
#pragma unroll
            for (int ni = 0; ni < 2; ++ni)
#pragma unroll
                for (int ks = 0; ks < 2; ++ks)
                    acc[mi + 4][ni] = __builtin_amdgcn_mfma_f32_16x16x32_bf16(
                        afB[mi][ks], b0[ni][ks], acc[mi + 4][ni], 0, 0, 0);
        __builtin_amdgcn_s_setprio(0);

        // S7b: b0 <- B0(t+1)   (4 late reads; first use is late in next C1)
        if (more) {
#pragma unroll
            for (int ni = 0; ni < 2; ++ni) {
                b0[ni][0] = LD8(cbn + boffs + ni * 2048 + cx0);
                b0[ni][1] = LD8(cbn + boffs + ni * 2048 + cx1);
            }
        }
    }

    // ---- epilogue: C/D layout col=lane&15, row=(lane>>4)*4+j
#pragma unroll
    for (int ni = 0; ni < 4; ++ni) {
        const int col = n0 + wn * 64 + ni * 16 + fr;
        const float bv = bias[col];
#pragma unroll
        for (int mi = 0; mi < 8; ++mi) {
            const int row = m0 + wm * 128 + mi * 16 + fq * 4;
#pragma unroll
            for (int j = 0; j < 4; ++j)
                out[(size_t)(row + j) * N_DIM + col] = acc[mi][ni][j] + bv;
        }
    }
#undef STAGE_TILE_P
#undef ADVANCE_PTRS
#undef LD8
}

// ---------------- fallback (round-1 fused kernel, ws too small) ----------------
#define FBM 128
#define FBK 64
#define LDS_K (FBK + 8)
__global__ __launch_bounds__(256, 2) void q4gemm_kernel(
    const float* __restrict__ x, const int* __restrict__ qweight,
    const int* __restrict__ qzeros, const float* __restrict__ scales,
    const float* __restrict__ bias, float* __restrict__ out)
{
    __shared__ unsigned short As[FBM][LDS_K];
    __shared__ unsigned short Bs[FBM][LDS_K];
    const int tid = threadIdx.x, lane = tid & 63, wave = tid >> 6;
    const int wr = wave >> 1, wc = wave & 1;
    const int m0 = blockIdx.x * FBM, nn0 = blockIdx.y * FBM;
    const int fr = lane & 15, fq = lane >> 4, kfrag = fq << 3;
    f32x4 acc[4][4];
#pragma unroll
    for (int i = 0; i < 4; i++)
#pragma unroll
        for (int j = 0; j < 4; j++) acc[i][j] = (f32x4){0.f, 0.f, 0.f, 0.f};
    for (int k0 = 0; k0 < K_DIM; k0 += FBK) {
        const int g = k0 >> 7;
#pragma unroll
        for (int i = 0; i < 8; i++) {
            int idx = tid + i * 256, row = idx >> 4, c4 = (idx & 15) << 2;
            const float4 v = *reinterpret_cast<const float4*>(
                &x[(size_t)(m0 + row) * K_DIM + k0 + c4]);
            ushort4 h; h.x = f2bf(v.x); h.y = f2bf(v.y); h.z = f2bf(v.z); h.w = f2bf(v.w);
            *reinterpret_cast<ushort4*>(&As[row][c4]) = h;
        }
#pragma unroll
        for (int i = 0; i < 4; i++) {
            int idx = tid + i * 256, krl = idx >> 7, nl = idx & 127, n = nn0 + nl;
            int q = qweight[(size_t)(k0 / 8 + krl) * N_DIM + n];
            float sc = scales[(size_t)g * N_DIM + n];
            int zq = qzeros[(size_t)g * (N_DIM / 8) + (n >> 3)];
            int z = ((zq >> ((n & 7) * 4)) & 0xF) + 1;
            bf16x8 wv;
#pragma unroll
            for (int s = 0; s < 8; s++)
                wv[s] = (short)f2bf(sc * (float)(((q >> (s * 4)) & 0xF) - z));
            *reinterpret_cast<bf16x8*>(&Bs[nl][krl * 8]) = wv;
        }
        __syncthreads();
        bf16x8 a_frag[2][4], b_frag[2][4];
#pragma unroll
        for (int ks = 0; ks < 2; ks++) {
            const int kb = ks * 32 + kfrag;
#pragma unroll
            for (int mi = 0; mi < 4; mi++)
                a_frag[ks][mi] = *reinterpret_cast<const bf16x8*>(&As[wr * 64 + mi * 16 + fr][kb]);
#pragma unroll
            for (int ni = 0; ni < 4; ni++)
                b_frag[ks][ni] = *reinterpret_cast<const bf16x8*>(&Bs[wc * 64 + ni * 16 + fr][kb]);
        }
#pragma unroll
        for (int ks = 0; ks < 2; ks++)
#pragma unroll
            for (int mi = 0; mi < 4; mi++)
#pragma unroll
                for (int ni = 0; ni < 4; ni++)
                    acc[mi][ni] = __builtin_amdgcn_mfma_f32_16x16x32_bf16(
                        a_frag[ks][mi], b_frag[ks][ni], acc[mi][ni], 0, 0, 0);
        __syncthreads();
    }
#pragma unroll
    for (int ni = 0; ni < 4; ni++) {
        const int col = nn0 + wc * 64 + ni * 16 + fr;
        const float bv = bias[col];
#pragma unroll
        for (int mi = 0; mi < 4; mi++)
#pragma unroll
            for (int j = 0; j < 4; j++) {
                const int row = m0 + wr * 64 + mi * 16 + fq * 4 + j;
                out[(size_t)row * N_DIM + col] = acc[mi][ni][j] + bv;
            }
    }
}

extern "C" void kernel_launch(void* const* d_in, const int* in_sizes, int n_in,
                              void* d_out, int out_size, void* d_ws, size_t ws_size,
                              hipStream_t stream) {
    const float* x       = (const float*)d_in[0];
    const int*   qweight = (const int*)d_in[1];
    const int*   qzeros  = (const int*)d_in[2];
    const float* scales  = (const float*)d_in[3];
    const float* bias    = (const float*)d_in[5];
    float*       out     = (float*)d_out;

    const size_t xbf_bytes = (size_t)TOKENS * K_DIM * 2;   // 64 MB
    const size_t wt_bytes  = (size_t)N_DIM * K_DIM * 2;    // 32 MB

    if (ws_size >= xbf_bytes + wt_bytes) {
        unsigned short* xbf = (unsigned short*)d_ws;
        unsigned short* wt  = (unsigned short*)((char*)d_ws + xbf_bytes);

        prep_kernel<<<CVT_BLOCKS + (N_DIM * (K_DIM / 64)) / 256, 256, 0, stream>>>(
            x, xbf, qweight, qzeros, scales, wt);
        dim3 grid(TOKENS / BM, N_DIM / BN);
        gemm_sp_kernel<<<grid, dim3(512), 0, stream>>>(xbf, wt, bias, out);
    } else {
        q4gemm_kernel<<<dim3(TOKENS / FBM, N_DIM / FBM), dim3(256), 0, stream>>>(
            x, qweight, qzeros, scales, bias, out);
    }
}

// Round 14
// 270.755 us; speedup vs baseline: 1.3969x; 1.3969x over previous
//
#include <hip/hip_runtime.h>
#include <hip/hip_bf16.h>
#include <stdint.h>

#define K_DIM 4096
#define N_DIM 4096
#define TOKENS 8192

#define BM 256
#define BN 256
#define BK 64
#define NT (K_DIM / BK)        // 64 k-tiles

// LDS: 2 bufs x { A[256r][128B row] | B[256c][128B row] } = 2 x 64 KB.
// 16 KB units: A0(rows0-127) A1(rows128-255) B0 B1.  Row = 8 chunks of 16B,
// phys chunk = logical chunk ^ (row&7)  (conflict-free frag reads, verified r3-r10).
#define BUF_BYTES 65536
#define BOFS 32768
#define KH_BYTES 16384

typedef __attribute__((ext_vector_type(8))) short bf16x8;
typedef __attribute__((ext_vector_type(4))) float f32x4;

#define LDSV(p) ((__attribute__((address_space(3))) void*)(p))
#define GLBV(p) ((const __attribute__((address_space(1))) void*)(p))
#define MEMFENCE asm volatile("" ::: "memory")

__device__ inline unsigned short f2bf(float f) {
    union { float f; unsigned u; } v; v.f = f;
    unsigned r = v.u + 0x7FFF + ((v.u >> 16) & 1);   // RNE
    return (unsigned short)(r >> 16);
}

// ------- fused prepass: blocks [0,16384) convert x fp32->bf16;
//         blocks [16384,17408) GPTQ-dequant -> W^T bf16 [N][K] -------
#define CVT_BLOCKS 16384
__global__ __launch_bounds__(256) void prep_kernel(
    const float* __restrict__ x, unsigned short* __restrict__ xbf,
    const int* __restrict__ qweight, const int* __restrict__ qzeros,
    const float* __restrict__ scales, unsigned short* __restrict__ wt)
{
    const int b = blockIdx.x;
    if (b < CVT_BLOCKS) {
        size_t idx = ((size_t)b * 256 + threadIdx.x) * 8;
        const float4 v0 = *reinterpret_cast<const float4*>(&x[idx]);
        const float4 v1 = *reinterpret_cast<const float4*>(&x[idx + 4]);
        ushort4 h0, h1;
        h0.x = f2bf(v0.x); h0.y = f2bf(v0.y); h0.z = f2bf(v0.z); h0.w = f2bf(v0.w);
        h1.x = f2bf(v1.x); h1.y = f2bf(v1.y); h1.z = f2bf(v1.z); h1.w = f2bf(v1.w);
        *reinterpret_cast<ushort4*>(&xbf[idx]) = h0;
        *reinterpret_cast<ushort4*>(&xbf[idx + 4]) = h1;
    } else {
        const int idx = (b - CVT_BLOCKS) * 256 + threadIdx.x;
        const int kb = idx >> 12;            // 0..63  (block of 64 k)
        const int n  = idx & (N_DIM - 1);
        const int kr0 = kb * 8;
        const int g = kb >> 1;               // group: (kb*64)/128
        const float sc = scales[(size_t)g * N_DIM + n];
        const int zq = qzeros[(size_t)g * (N_DIM / 8) + (n >> 3)];
        const float zf = (float)(((zq >> ((n & 7) * 4)) & 0xF) + 1);

        unsigned short* dst = &wt[(size_t)n * K_DIM + kb * 64];
#pragma unroll
        for (int i = 0; i < 8; i++) {
            const int q = qweight[(size_t)(kr0 + i) * N_DIM + n];
            bf16x8 wv;
#pragma unroll
            for (int s = 0; s < 8; s++) {
                const float w = (float)((q >> (s * 4)) & 0xF) - zf;
                wv[s] = (short)f2bf(sc * w);
            }
            *reinterpret_cast<bf16x8*>(&dst[i * 8]) = wv;
        }
    }
}

// ----- main GEMM: 256x256, 8 waves, 1-barrier/tile software-pipelined, dbuf-2 -----
// r7/r10 verified schedule, 16x16x32 MFMA, identity block mapping.
__global__ __launch_bounds__(512, 2) void gemm_sp_kernel(
    const unsigned short* __restrict__ xbf, const unsigned short* __restrict__ wt,
    const float* __restrict__ bias, float* __restrict__ out)
{
    __shared__ __align__(16) char lds[2 * BUF_BYTES];   // 128 KB

    const int tid  = threadIdx.x;
    const int lane = tid & 63;
    const int wave = tid >> 6;
    const int wm = wave >> 2;        // 0..1 : 128-row M slice
    const int wn = wave & 3;         // 0..3 : 64-col N slice
    const int fr = lane & 15;
    const int fq = lane >> 4;

    const int m0 = blockIdx.x * BM;
    const int n0 = blockIdx.y * BN;

    // staging geometry: gload covers 8 rows x 8 chunks; source chunk pre-permuted
    const int srow = wave * 8 + (lane >> 3);
    const int k8   = (lane & 7) ^ ((lane >> 3) & 7);

    // fragment read offsets
    const int cx0 = (fq ^ (fr & 7)) << 4;          // ks=0 chunk byte
    const int cx1 = ((4 + fq) ^ (fr & 7)) << 4;    // ks=1 chunk byte
    const int aoffs = wm * KH_BYTES + fr * 128;                              // + mi*2048
    const int boffs = BOFS + (wn >> 1) * KH_BYTES + ((wn & 1) * 64 + fr) * 128;  // + ni*2048

    f32x4 acc[8][4];
#pragma unroll
    for (int i = 0; i < 8; i++)
#pragma unroll
        for (int j = 0; j < 4; j++) acc[i][j] = (f32x4){0.f, 0.f, 0.f, 0.f};

#define STAGE_AU(tt, u) do {                                                    \
    const int _b = (((tt) & 1) * BUF_BYTES) + (u) * KH_BYTES;                   \
    const size_t _r = (size_t)(m0 + (u) * 128 + srow);                          \
    const int _k = (tt) * BK + k8 * 8;                                          \
    __builtin_amdgcn_global_load_lds(GLBV(xbf + _r * K_DIM + _k),               \
        LDSV(lds + _b + wave * 1024), 16, 0, 0);                                \
    __builtin_amdgcn_global_load_lds(GLBV(xbf + (_r + 64) * K_DIM + _k),        \
        LDSV(lds + _b + 8192 + wave * 1024), 16, 0, 0); } while (0)

#define STAGE_BU(tt, u) do {                                                    \
    const int _b = (((tt) & 1) * BUF_BYTES) + BOFS + (u) * KH_BYTES;            \
    const size_t _r = (size_t)(n0 + (u) * 128 + srow);                          \
    const int _k = (tt) * BK + k8 * 8;                                          \
    __builtin_amdgcn_global_load_lds(GLBV(wt + _r * K_DIM + _k),                \
        LDSV(lds + _b + wave * 1024), 16, 0, 0);                                \
    __builtin_amdgcn_global_load_lds(GLBV(wt + (_r + 64) * K_DIM + _k),         \
        LDSV(lds + _b + 8192 + wave * 1024), 16, 0, 0); } while (0)

#define STAGE_TILE(tt) do { STAGE_AU(tt, 0); STAGE_AU(tt, 1);                   \
                            STAGE_BU(tt, 0); STAGE_BU(tt, 1); } while (0)

#define LD8(off) (*reinterpret_cast<const bf16x8*>(lds + (off)))

    // ---- prologue: stage tile 0, wait, barrier, preload afA/b0/b1 of tile 0
    STAGE_TILE(0);
    asm volatile("s_waitcnt vmcnt(0)" ::: "memory");
    __builtin_amdgcn_s_barrier();

    bf16x8 afA[4][2], afB[4][2], b0[2][2], b1[2][2];
#pragma unroll
    for (int mi = 0; mi < 4; ++mi) {
        afA[mi][0] = LD8(aoffs + mi * 2048 + cx0);
        afA[mi][1] = LD8(aoffs + mi * 2048 + cx1);
    }
#pragma unroll
    for (int ni = 0; ni < 2; ++ni) {
        b0[ni][0] = LD8(boffs + ni * 2048 + cx0);
        b0[ni][1] = LD8(boffs + ni * 2048 + cx1);
        b1[ni][0] = LD8(boffs + (ni + 2) * 2048 + cx0);
        b1[ni][1] = LD8(boffs + (ni + 2) * 2048 + cx1);
    }

#pragma unroll 1
    for (int t = 0; t < NT; ++t) {
        const int cb  = (t & 1) * BUF_BYTES;
        const int cbn = cb ^ BUF_BYTES;
        const bool more = (t + 1) < NT;

        // S1: stage whole tile t+1 into the opposite buffer
        if (more) STAGE_TILE(t + 1);

        // S2: afB <- af1(t)
#pragma unroll
        for (int mi = 0; mi < 4; ++mi) {
            afB[mi][0] = LD8(cb + aoffs + (mi + 4) * 2048 + cx0);
            afB[mi][1] = LD8(cb + aoffs + (mi + 4) * 2048 + cx1);
        }
        __builtin_amdgcn_sched_barrier(0);

        // C1: afA x b1 -> Q01 FIRST (b1 long-drained), then afA x b0 -> Q00
        __builtin_amdgcn_s_setprio(1);
#pragma unroll
        for (int mi = 0; mi < 4; ++mi)
#pragma unroll
            for (int ni = 0; ni < 2; ++ni)
#pragma unroll
                for (int ks = 0; ks < 2; ++ks)
                    acc[mi][ni + 2] = __builtin_amdgcn_mfma_f32_16x16x32_bf16(
                        afA[mi][ks], b1[ni][ks], acc[mi][ni + 2], 0, 0, 0);
#pragma unroll
        for (int mi = 0; mi < 4; ++mi)
#pragma unroll
            for (int ni = 0; ni < 2; ++ni)
#pragma unroll
                for (int ks = 0; ks < 2; ++ks)
                    acc[mi][ni] = __builtin_amdgcn_mfma_f32_16x16x32_bf16(
                        afA[mi][ks], b0[ni][ks], acc[mi][ni], 0, 0, 0);
        __builtin_amdgcn_s_setprio(0);
        __builtin_amdgcn_sched_barrier(0);

        // C2: afB x b1 -> Q11   (16 MFMA; b1 dies here)
        __builtin_amdgcn_s_setprio(1);
#pragma unroll
        for (int mi = 0; mi < 4; ++mi)
#pragma unroll
            for (int ni = 0; ni < 2; ++ni)
#pragma unroll
                for (int ks = 0; ks < 2; ++ks)
                    acc[mi + 4][ni + 2] = __builtin_amdgcn_mfma_f32_16x16x32_bf16(
                        afB[mi][ks], b1[ni][ks], acc[mi + 4][ni + 2], 0, 0, 0);
        __builtin_amdgcn_s_setprio(0);

        // boundary: own stages (issued a 48-MFMA window ago) land; sync all waves
        asm volatile("s_waitcnt vmcnt(0)" ::: "memory");
        MEMFENCE; __builtin_amdgcn_s_barrier(); MEMFENCE;

        // S7a: afA <- af0(t+1), b1 <- B1(t+1)   (12 reads, overlap C3)
        if (more) {
#pragma unroll
            for (int mi = 0; mi < 4; ++mi) {
                afA[mi][0] = LD8(cbn + aoffs + mi * 2048 + cx0);
                afA[mi][1] = LD8(cbn + aoffs + mi * 2048 + cx1);
            }
#pragma unroll
            for (int ni = 0; ni < 2; ++ni) {
                b1[ni][0] = LD8(cbn + boffs + (ni + 2) * 2048 + cx0);
                b1[ni][1] = LD8(cbn + boffs + (ni + 2) * 2048 + cx1);
            }
        }
        __builtin_amdgcn_sched_barrier(0);

        // C3: afB x b0 -> Q10   (16 MFMA; b0 dies here)
        __builtin_amdgcn_s_setprio(1);
#pragma unroll
        for (int mi = 0; mi < 4; ++mi)
#pragma unroll
            for (int ni = 0; ni < 2; ++ni)
#pragma unroll
                for (int ks = 0; ks < 2; ++ks)
                    acc[mi + 4][ni] = __builtin_amdgcn_mfma_f32_16x16x32_bf16(
                        afB[mi][ks], b0[ni][ks], acc[mi + 4][ni], 0, 0, 0);
        __builtin_amdgcn_s_setprio(0);

        // S7b: b0 <- B0(t+1)   (4 late reads; first use is late in next C1)
        if (more) {
#pragma unroll
            for (int ni = 0; ni < 2; ++ni) {
                b0[ni][0] = LD8(cbn + boffs + ni * 2048 + cx0);
                b0[ni][1] = LD8(cbn + boffs + ni * 2048 + cx1);
            }
        }
    }

    // ---- epilogue: C/D layout col=lane&15, row=(lane>>4)*4+j
#pragma unroll
    for (int ni = 0; ni < 4; ++ni) {
        const int col = n0 + wn * 64 + ni * 16 + fr;
        const float bv = bias[col];
#pragma unroll
        for (int mi = 0; mi < 8; ++mi) {
            const int row = m0 + wm * 128 + mi * 16 + fq * 4;
#pragma unroll
            for (int j = 0; j < 4; ++j)
                out[(size_t)(row + j) * N_DIM + col] = acc[mi][ni][j] + bv;
        }
    }
#undef STAGE_AU
#undef STAGE_BU
#undef STAGE_TILE
#undef LD8
}

// ---------------- fallback (round-1 fused kernel, ws too small) ----------------
#define FBM 128
#define FBK 64
#define LDS_K (FBK + 8)
__global__ __launch_bounds__(256, 2) void q4gemm_kernel(
    const float* __restrict__ x, const int* __restrict__ qweight,
    const int* __restrict__ qzeros, const float* __restrict__ scales,
    const float* __restrict__ bias, float* __restrict__ out)
{
    __shared__ unsigned short As[FBM][LDS_K];
    __shared__ unsigned short Bs[FBM][LDS_K];
    const int tid = threadIdx.x, lane = tid & 63, wave = tid >> 6;
    const int wr = wave >> 1, wc = wave & 1;
    const int m0 = blockIdx.x * FBM, nn0 = blockIdx.y * FBM;
    const int fr = lane & 15, fq = lane >> 4, kfrag = fq << 3;
    f32x4 acc[4][4];
#pragma unroll
    for (int i = 0; i < 4; i++)
#pragma unroll
        for (int j = 0; j < 4; j++) acc[i][j] = (f32x4){0.f, 0.f, 0.f, 0.f};
    for (int k0 = 0; k0 < K_DIM; k0 += FBK) {
        const int g = k0 >> 7;
#pragma unroll
        for (int i = 0; i < 8; i++) {
            int idx = tid + i * 256, row = idx >> 4, c4 = (idx & 15) << 2;
            const float4 v = *reinterpret_cast<const float4*>(
                &x[(size_t)(m0 + row) * K_DIM + k0 + c4]);
            ushort4 h; h.x = f2bf(v.x); h.y = f2bf(v.y); h.z = f2bf(v.z); h.w = f2bf(v.w);
            *reinterpret_cast<ushort4*>(&As[row][c4]) = h;
        }
#pragma unroll
        for (int i = 0; i < 4; i++) {
            int idx = tid + i * 256, krl = idx >> 7, nl = idx & 127, n = nn0 + nl;
            int q = qweight[(size_t)(k0 / 8 + krl) * N_DIM + n];
            float sc = scales[(size_t)g * N_DIM + n];
            int zq = qzeros[(size_t)g * (N_DIM / 8) + (n >> 3)];
            int z = ((zq >> ((n & 7) * 4)) & 0xF) + 1;
            bf16x8 wv;
#pragma unroll
            for (int s = 0; s < 8; s++)
                wv[s] = (short)f2bf(sc * (float)(((q >> (s * 4)) & 0xF) - z));
            *reinterpret_cast<bf16x8*>(&Bs[nl][krl * 8]) = wv;
        }
        __syncthreads();
        bf16x8 a_frag[2][4], b_frag[2][4];
#pragma unroll
        for (int ks = 0; ks < 2; ks++) {
            const int kb = ks * 32 + kfrag;
#pragma unroll
            for (int mi = 0; mi < 4; mi++)
                a_frag[ks][mi] = *reinterpret_cast<const bf16x8*>(&As[wr * 64 + mi * 16 + fr][kb]);
#pragma unroll
            for (int ni = 0; ni < 4; ni++)
                b_frag[ks][ni] = *reinterpret_cast<const bf16x8*>(&Bs[wc * 64 + ni * 16 + fr][kb]);
        }
#pragma unroll
        for (int ks = 0; ks < 2; ks++)
#pragma unroll
            for (int mi = 0; mi < 4; mi++)
#pragma unroll
                for (int ni = 0; ni < 4; ni++)
                    acc[mi][ni] = __builtin_amdgcn_mfma_f32_16x16x32_bf16(
                        a_frag[ks][mi], b_frag[ks][ni], acc[mi][ni], 0, 0, 0);
        __syncthreads();
    }
#pragma unroll
    for (int ni = 0; ni < 4; ni++) {
        const int col = nn0 + wc * 64 + ni * 16 + fr;
        const float bv = bias[col];
#pragma unroll
        for (int mi = 0; mi < 4; mi++)
#pragma unroll
            for (int j = 0; j < 4; j++) {
                const int row = m0 + wr * 64 + mi * 16 + fq * 4 + j;
                out[(size_t)row * N_DIM + col] = acc[mi][ni][j] + bv;
            }
    }
}

extern "C" void kernel_launch(void* const* d_in, const int* in_sizes, int n_in,
                              void* d_out, int out_size, void* d_ws, size_t ws_size,
                              hipStream_t stream) {
    const float* x       = (const float*)d_in[0];
    const int*   qweight = (const int*)d_in[1];
    const int*   qzeros  = (const int*)d_in[2];
    const float* scales  = (const float*)d_in[3];
    const float* bias    = (const float*)d_in[5];
    float*       out     = (float*)d_out;

    const size_t xbf_bytes = (size_t)TOKENS * K_DIM * 2;   // 64 MB
    const size_t wt_bytes  = (size_t)N_DIM * K_DIM * 2;    // 32 MB

    if (ws_size >= xbf_bytes + wt_bytes) {
        unsigned short* xbf = (unsigned short*)d_ws;
        unsigned short* wt  = (unsigned short*)((char*)d_ws + xbf_bytes);

        prep_kernel<<<CVT_BLOCKS + (N_DIM * (K_DIM / 64)) / 256, 256, 0, stream>>>(
            x, xbf, qweight, qzeros, scales, wt);
        dim3 grid(TOKENS / BM, N_DIM / BN);
        gemm_sp_kernel<<<grid, dim3(512), 0, stream>>>(xbf, wt, bias, out);
    } else {
        q4gemm_kernel<<<dim3(TOKENS / FBM, N_DIM / FBM), dim3(256), 0, stream>>>(
            x, qweight, qzeros, scales, bias, out);
    }
}